// Round 6
// baseline (194.532 us; speedup 1.0000x reference)
//
#include <hip/hip_runtime.h>
#include <math.h>

#define NATOMS 5
#define NEXP 18
#define NBEAD 4
#define EPSV 1e-8f
#define ML2 (0.02f * 0.02f)

// Pack per (expert,bead): 8 triplets, one 16-bit entry each in an int4.
// entry: oi | oj<<4 | ok<<8 | okflag<<12, offsets premultiplied by 3.
__global__ void pack_tables(const int* __restrict__ trip, const int* __restrict__ valid,
                            int4* __restrict__ ptbl) {
    int c = blockIdx.x * blockDim.x + threadIdx.x;
    if (c < NEXP * NBEAD) {
        unsigned w[4] = {0u, 0u, 0u, 0u};
#pragma unroll
        for (int t = 0; t < 8; t++) {
            int b = c * 8 + t;
            int i = trip[b * 3 + 0], j = trip[b * 3 + 1], k = trip[b * 3 + 2];
            unsigned ok = (i >= 0 && j >= 0 && k >= 0 && valid[b] > 0) ? 1u : 0u;
            unsigned oi = 3u * (unsigned)min(max(i, 0), NATOMS - 1);
            unsigned oj = 3u * (unsigned)min(max(j, 0), NATOMS - 1);
            unsigned ov = 3u * (unsigned)min(max(k, 0), NATOMS - 1);
            unsigned e = oi | (oj << 4) | (ov << 8) | (ok << 12);
            w[t >> 1] |= e << ((t & 1) * 16);
        }
        ptbl[c] = make_int4((int)w[0], (int)w[1], (int)w[2], (int)w[3]);
    }
}

// Per-row loss: atom MSE from registers, angle part via dynamic gathers from
// the thread's PRIVATE LDS slice (stride 33 dwords -> conflict-free banking).
__device__ __forceinline__ float row_loss(const float* __restrict__ T,
                                          const float* __restrict__ P,
                                          unsigned mbits, int4 pk, float* __restrict__ st) {
    // ---- atom MSE (mask binary -> exact bit logic) ----
    float num_a = 0.f, den_a = 0.f;
    unsigned avm2 = 0u;  // validity bit at premultiplied offset 3*a
#pragma unroll
    for (int a = 0; a < 5; a++) {
        unsigned mb = (mbits >> (3 * a)) & 7u;
        float d0 = T[3 * a + 0] - P[3 * a + 0];
        float d1 = T[3 * a + 1] - P[3 * a + 1];
        float d2 = T[3 * a + 2] - P[3 * a + 2];
        float se = (mb & 1u ? d0 * d0 : 0.f) + (mb & 2u ? d1 * d1 : 0.f) +
                   (mb & 4u ? d2 * d2 : 0.f);
        if (mb) { num_a += se; den_a += 1.f; avm2 |= 1u << (3 * a); }
    }
    float res = num_a / (den_a + EPSV);

    // Spill row to private slice: T at [0,15), P at [16,31).
#pragma unroll
    for (int c = 0; c < 15; c++) st[c] = T[c];
#pragma unroll
    for (int c = 0; c < 15; c++) st[16 + c] = P[c];

    unsigned tw0 = (unsigned)pk.x, tw1 = (unsigned)pk.y;
    unsigned tw2 = (unsigned)pk.z, tw3 = (unsigned)pk.w;

    float num_g = 0.f, den_g = 0.f;
#pragma unroll
    for (int t = 0; t < 8; t++) {
        unsigned wrd = (t < 2) ? tw0 : (t < 4) ? tw1 : (t < 6) ? tw2 : tw3;
        unsigned e = (wrd >> ((t & 1) * 16)) & 0xffffu;
        int oi = e & 15, oj = (e >> 4) & 15, ov = (e >> 8) & 15;
        bool wok = ((e >> 12) & 1u) != 0u;

        float tix = st[oi], tiy = st[oi + 1], tiz = st[oi + 2];
        float tjx = st[oj], tjy = st[oj + 1], tjz = st[oj + 2];
        float tkx = st[ov], tky = st[ov + 1], tkz = st[ov + 2];
        float pix = st[16 + oi], piy = st[17 + oi], piz = st[18 + oi];
        float pjx = st[16 + oj], pjy = st[17 + oj], pjz = st[18 + oj];
        float pkx = st[16 + ov], pky = st[17 + ov], pkz = st[18 + ov];

        float v1tx = tix - tjx, v1ty = tiy - tjy, v1tz = tiz - tjz;
        float v2tx = tkx - tjx, v2ty = tky - tjy, v2tz = tkz - tjz;
        float v1px = pix - pjx, v1py = piy - pjy, v1pz = piz - pjz;
        float v2px = pkx - pjx, v2py = pky - pjy, v2pz = pkz - pjz;

        float l1t = fmaf(v1tx, v1tx, fmaf(v1ty, v1ty, v1tz * v1tz));
        float l2t = fmaf(v2tx, v2tx, fmaf(v2ty, v2ty, v2tz * v2tz));
        float l1p = fmaf(v1px, v1px, fmaf(v1py, v1py, v1pz * v1pz));
        float l2p = fmaf(v2px, v2px, fmaf(v2py, v2py, v2pz * v2pz));

        bool okv = wok && ((avm2 >> oi) & 1) && ((avm2 >> oj) & 1) &&
                   ((avm2 >> ov) & 1) && (l1t > ML2) && (l2t > ML2) &&
                   (l1p > ML2) && (l2p > ML2);

        float rt = __builtin_amdgcn_rsqf(fmaxf(l1t, ML2) * fmaxf(l2t, ML2));
        float rp = __builtin_amdgcn_rsqf(fmaxf(l1p, ML2) * fmaxf(l2p, ML2));

        float dott = fmaf(v1tx, v2tx, fmaf(v1ty, v2ty, v1tz * v2tz));
        float dotp = fmaf(v1px, v2px, fmaf(v1py, v2py, v1pz * v2pz));
        float cut = dott * rt;
        float cup = dotp * rp;
        float cost = fminf(fmaxf(cut, -1.f + 1e-6f), 1.f - 1e-6f);
        float cosp = fminf(fmaxf(cup, -1.f + 1e-6f), 1.f - 1e-6f);
        float sint = __builtin_amdgcn_sqrtf(fmaxf(fmaf(-cut, cut, 1.f), 0.f));
        float sinp = __builtin_amdgcn_sqrtf(fmaxf(fmaf(-cup, cup, 1.f), 0.f));

        float dc = cosp - cost, dsn = sinp - sint;
        if (okv) { num_g += fmaf(dc, dc, dsn * dsn); den_g += 1.f; }
    }
    return res + num_g / (den_g + EPSV);
}

// Two rows per thread, all loads for both rows issued before either compute:
// 2x memory-level parallelism per wave, half the waves. Barrier-free.
// LDS: 256 * 33 * 4 = 33792 B -> 4 blocks/CU; VGPR capped at 128 by (256,4).
__global__ __launch_bounds__(256, 4) void loss_kernel(
    const float* __restrict__ xin, const float* __restrict__ y_true,
    const float* __restrict__ y_pred, const float* __restrict__ mask,
    const int4* __restrict__ ptbl, float* __restrict__ partial, int n) {
    __shared__ float scr[256 * 33];

    const int tid = threadIdx.x;
    const int row0 = blockIdx.x * 512 + tid;
    const int row1 = row0 + 256;
    const bool v0 = row0 < n, v1 = row1 < n;
    float* st = scr + tid * 33;  // stride 33 -> (33*tid+o)%32 spreads banks

    float T0[15], P0[15], T1[15], P1[15];
    unsigned mb0 = 0u, mb1 = 0u;
    float2 gb0 = make_float2(0.f, 0.f), gb1 = make_float2(0.f, 0.f);

    // ---- issue ALL loads for both rows up front ----
    if (v0) {
        const size_t rb = (size_t)row0 * 15;
#pragma unroll
        for (int c = 0; c < 15; c++) T0[c] = y_true[rb + c];
#pragma unroll
        for (int c = 0; c < 15; c++) P0[c] = y_pred[rb + c];
        gb0 = *(const float2*)(xin + (size_t)row0 * 38 + 36);
        float M0[15];
#pragma unroll
        for (int c = 0; c < 15; c++) M0[c] = mask[rb + c];
#pragma unroll
        for (int c = 0; c < 15; c++) mb0 |= (M0[c] > 0.f ? 1u : 0u) << c;
    }
    if (v1) {
        const size_t rb = (size_t)row1 * 15;
#pragma unroll
        for (int c = 0; c < 15; c++) T1[c] = y_true[rb + c];
#pragma unroll
        for (int c = 0; c < 15; c++) P1[c] = y_pred[rb + c];
        gb1 = *(const float2*)(xin + (size_t)row1 * 38 + 36);
        float M1[15];
#pragma unroll
        for (int c = 0; c < 15; c++) M1[c] = mask[rb + c];
#pragma unroll
        for (int c = 0; c < 15; c++) mb1 |= (M1[c] > 0.f ? 1u : 0u) << c;
    }

    // ---- gate decode + table fetch (tiny, L1-resident) ----
    int4 pk0 = make_int4(0, 0, 0, 0), pk1 = make_int4(0, 0, 0, 0);
    if (v0) {
        float beadf = isfinite(gb0.x) ? gb0.x : 0.f;
        float gatef = isfinite(gb0.y) ? gb0.y : 0.f;
        gatef = fminf(fmaxf(gatef, -1e6f), 1e6f);
        beadf = fminf(fmaxf(beadf, -1e6f), 1e6f);
        int rid = min(max((int)rintf(gatef) - 1, 0), NEXP - 1);
        int bid = min(max((int)rintf(beadf), 0), NBEAD - 1);
        pk0 = ptbl[rid * NBEAD + bid];
    }
    if (v1) {
        float beadf = isfinite(gb1.x) ? gb1.x : 0.f;
        float gatef = isfinite(gb1.y) ? gb1.y : 0.f;
        gatef = fminf(fmaxf(gatef, -1e6f), 1e6f);
        beadf = fminf(fmaxf(beadf, -1e6f), 1e6f);
        int rid = min(max((int)rintf(gatef) - 1, 0), NEXP - 1);
        int bid = min(max((int)rintf(beadf), 0), NBEAD - 1);
        pk1 = ptbl[rid * NBEAD + bid];
    }

    // ---- compute row0 while row1 loads are still in flight ----
    float result = 0.f;
    if (v0) result += row_loss(T0, P0, mb0, pk0, st);
    if (v1) result += row_loss(T1, P1, mb1, pk1, st);

    // ---- block reduction ----
#pragma unroll
    for (int off = 32; off > 0; off >>= 1)
        result += __shfl_down(result, off, 64);
    __syncthreads();  // protect scr reuse as red[]
    float* red = scr;
    int lane = tid & 63, wv = tid >> 6;
    if (lane == 0) red[wv] = result;
    __syncthreads();
    if (tid == 0) partial[blockIdx.x] = red[0] + red[1] + red[2] + red[3];
}

__global__ __launch_bounds__(256) void reduce_kernel(const float* __restrict__ partial,
                                                     float* __restrict__ out, int nblocks,
                                                     float inv_n) {
    __shared__ float red[4];
    float s = 0.f;
    for (int i = threadIdx.x; i < nblocks; i += 256) s += partial[i];
#pragma unroll
    for (int off = 32; off > 0; off >>= 1) s += __shfl_down(s, off, 64);
    int lane = threadIdx.x & 63, wv = threadIdx.x >> 6;
    if (lane == 0) red[wv] = s;
    __syncthreads();
    if (threadIdx.x == 0) out[0] = (red[0] + red[1] + red[2] + red[3]) * inv_n;
}

extern "C" void kernel_launch(void* const* d_in, const int* in_sizes, int n_in,
                              void* d_out, int out_size, void* d_ws, size_t ws_size,
                              hipStream_t stream) {
    const float* x = (const float*)d_in[0];
    const float* y_true = (const float*)d_in[1];
    const float* y_pred = (const float*)d_in[2];
    const float* mask = (const float*)d_in[3];
    const int* trip = (const int*)d_in[4];
    const int* valid = (const int*)d_in[5];
    float* out = (float*)d_out;

    int4* ptbl = (int4*)d_ws;                       // 72 * 16 B
    float* partial = (float*)((char*)d_ws + 4096);  // block partials

    const int n = in_sizes[1] / 15;  // N rows (y_true is N x 15)
    const int blocks = (n + 511) / 512;

    pack_tables<<<1, 128, 0, stream>>>(trip, valid, ptbl);
    loss_kernel<<<blocks, 256, 0, stream>>>(x, y_true, y_pred, mask, ptbl, partial, n);
    reduce_kernel<<<1, 256, 0, stream>>>(partial, out, blocks, 1.0f / (float)n);
}

// Round 7
// 188.601 us; speedup vs baseline: 1.0314x; 1.0314x over previous
//
#include <hip/hip_runtime.h>
#include <math.h>

#define NATOMS 5
#define NEXP 18
#define NBEAD 4
#define EPSV 1e-8f
#define ML2 (0.02f * 0.02f)

typedef float vf4 __attribute__((ext_vector_type(4), aligned(4)));
typedef float vf2 __attribute__((ext_vector_type(2), aligned(4)));

// Pack per (expert,bead): 8 triplets, one 16-bit entry each in an int4.
// entry: oi | oj<<4 | ok<<8 | okflag<<12, offsets premultiplied by 3.
__global__ void pack_tables(const int* __restrict__ trip, const int* __restrict__ valid,
                            int4* __restrict__ ptbl) {
    int c = blockIdx.x * blockDim.x + threadIdx.x;
    if (c < NEXP * NBEAD) {
        unsigned w[4] = {0u, 0u, 0u, 0u};
#pragma unroll
        for (int t = 0; t < 8; t++) {
            int b = c * 8 + t;
            int i = trip[b * 3 + 0], j = trip[b * 3 + 1], k = trip[b * 3 + 2];
            unsigned ok = (i >= 0 && j >= 0 && k >= 0 && valid[b] > 0) ? 1u : 0u;
            unsigned oi = 3u * (unsigned)min(max(i, 0), NATOMS - 1);
            unsigned oj = 3u * (unsigned)min(max(j, 0), NATOMS - 1);
            unsigned ov = 3u * (unsigned)min(max(k, 0), NATOMS - 1);
            unsigned e = oi | (oj << 4) | (ov << 8) | (ok << 12);
            w[t >> 1] |= e << ((t & 1) * 16);
        }
        ptbl[c] = make_int4((int)w[0], (int)w[1], (int)w[2], (int)w[3]);
    }
}

// Non-temporal row load: 15 floats as 3 x dwordx4 (unaligned-capable) + 3 dwords.
__device__ __forceinline__ void load_row_nt(const float* __restrict__ g, float* __restrict__ R) {
    const vf4* q = (const vf4*)g;
    vf4 a = __builtin_nontemporal_load(q);
    vf4 b = __builtin_nontemporal_load(q + 1);
    vf4 c = __builtin_nontemporal_load(q + 2);
    R[0] = a.x; R[1] = a.y; R[2] = a.z; R[3] = a.w;
    R[4] = b.x; R[5] = b.y; R[6] = b.z; R[7] = b.w;
    R[8] = c.x; R[9] = c.y; R[10] = c.z; R[11] = c.w;
    R[12] = __builtin_nontemporal_load(g + 12);
    R[13] = __builtin_nontemporal_load(g + 13);
    R[14] = __builtin_nontemporal_load(g + 14);
}

// Per-row loss: atom MSE from registers, angle part via dynamic gathers from
// the thread's PRIVATE LDS slice (stride 33 dwords -> conflict-free banking).
__device__ __forceinline__ float row_loss(const float* __restrict__ T,
                                          const float* __restrict__ P,
                                          unsigned mbits, int4 pk, float* __restrict__ st) {
    float num_a = 0.f, den_a = 0.f;
    unsigned avm2 = 0u;  // validity bit at premultiplied offset 3*a
#pragma unroll
    for (int a = 0; a < 5; a++) {
        unsigned mb = (mbits >> (3 * a)) & 7u;
        float d0 = T[3 * a + 0] - P[3 * a + 0];
        float d1 = T[3 * a + 1] - P[3 * a + 1];
        float d2 = T[3 * a + 2] - P[3 * a + 2];
        float se = (mb & 1u ? d0 * d0 : 0.f) + (mb & 2u ? d1 * d1 : 0.f) +
                   (mb & 4u ? d2 * d2 : 0.f);
        if (mb) { num_a += se; den_a += 1.f; avm2 |= 1u << (3 * a); }
    }
    float res = num_a / (den_a + EPSV);

    // Spill row to private slice: T at [0,15), P at [16,31).
#pragma unroll
    for (int c = 0; c < 15; c++) st[c] = T[c];
#pragma unroll
    for (int c = 0; c < 15; c++) st[16 + c] = P[c];

    unsigned tw0 = (unsigned)pk.x, tw1 = (unsigned)pk.y;
    unsigned tw2 = (unsigned)pk.z, tw3 = (unsigned)pk.w;

    float num_g = 0.f, den_g = 0.f;
#pragma unroll
    for (int t = 0; t < 8; t++) {
        unsigned wrd = (t < 2) ? tw0 : (t < 4) ? tw1 : (t < 6) ? tw2 : tw3;
        unsigned e = (wrd >> ((t & 1) * 16)) & 0xffffu;
        int oi = e & 15, oj = (e >> 4) & 15, ov = (e >> 8) & 15;
        bool wok = ((e >> 12) & 1u) != 0u;

        float tix = st[oi], tiy = st[oi + 1], tiz = st[oi + 2];
        float tjx = st[oj], tjy = st[oj + 1], tjz = st[oj + 2];
        float tkx = st[ov], tky = st[ov + 1], tkz = st[ov + 2];
        float pix = st[16 + oi], piy = st[17 + oi], piz = st[18 + oi];
        float pjx = st[16 + oj], pjy = st[17 + oj], pjz = st[18 + oj];
        float pkx = st[16 + ov], pky = st[17 + ov], pkz = st[18 + ov];

        float v1tx = tix - tjx, v1ty = tiy - tjy, v1tz = tiz - tjz;
        float v2tx = tkx - tjx, v2ty = tky - tjy, v2tz = tkz - tjz;
        float v1px = pix - pjx, v1py = piy - pjy, v1pz = piz - pjz;
        float v2px = pkx - pjx, v2py = pky - pjy, v2pz = pkz - pjz;

        float l1t = fmaf(v1tx, v1tx, fmaf(v1ty, v1ty, v1tz * v1tz));
        float l2t = fmaf(v2tx, v2tx, fmaf(v2ty, v2ty, v2tz * v2tz));
        float l1p = fmaf(v1px, v1px, fmaf(v1py, v1py, v1pz * v1pz));
        float l2p = fmaf(v2px, v2px, fmaf(v2py, v2py, v2pz * v2pz));

        bool okv = wok && ((avm2 >> oi) & 1) && ((avm2 >> oj) & 1) &&
                   ((avm2 >> ov) & 1) && (l1t > ML2) && (l2t > ML2) &&
                   (l1p > ML2) && (l2p > ML2);

        float rt = __builtin_amdgcn_rsqf(fmaxf(l1t, ML2) * fmaxf(l2t, ML2));
        float rp = __builtin_amdgcn_rsqf(fmaxf(l1p, ML2) * fmaxf(l2p, ML2));

        float dott = fmaf(v1tx, v2tx, fmaf(v1ty, v2ty, v1tz * v2tz));
        float dotp = fmaf(v1px, v2px, fmaf(v1py, v2py, v1pz * v2pz));
        float cut = dott * rt;
        float cup = dotp * rp;
        float cost = fminf(fmaxf(cut, -1.f + 1e-6f), 1.f - 1e-6f);
        float cosp = fminf(fmaxf(cup, -1.f + 1e-6f), 1.f - 1e-6f);
        float sint = __builtin_amdgcn_sqrtf(fmaxf(fmaf(-cut, cut, 1.f), 0.f));
        float sinp = __builtin_amdgcn_sqrtf(fmaxf(fmaf(-cup, cup, 1.f), 0.f));

        float dc = cosp - cost, dsn = sinp - sint;
        if (okv) { num_g += fmaf(dc, dc, dsn * dsn); den_g += 1.f; }
    }
    return res + num_g / (den_g + EPSV);
}

// Two rows per thread; ALL bulk loads non-temporal (bypass L1 fill path).
// LDS: 256 * 33 * 4 = 33792 B -> 4 blocks/CU.
__global__ __launch_bounds__(256, 4) void loss_kernel(
    const float* __restrict__ xin, const float* __restrict__ y_true,
    const float* __restrict__ y_pred, const float* __restrict__ mask,
    const int4* __restrict__ ptbl, float* __restrict__ partial, int n) {
    __shared__ float scr[256 * 33];

    const int tid = threadIdx.x;
    const int row0 = blockIdx.x * 512 + tid;
    const int row1 = row0 + 256;
    const bool v0 = row0 < n, v1 = row1 < n;
    float* st = scr + tid * 33;  // stride 33 -> (33*tid+o)%32 spreads banks

    float T0[15], P0[15], T1[15], P1[15];
    unsigned mb0 = 0u, mb1 = 0u;
    vf2 gb0, gb1;
    gb0.x = 0.f; gb0.y = 0.f; gb1.x = 0.f; gb1.y = 0.f;

    // ---- gates first (scattered single-line loads: worst latency) ----
    if (v0) gb0 = __builtin_nontemporal_load((const vf2*)(xin + (size_t)row0 * 38 + 36));
    if (v1) gb1 = __builtin_nontemporal_load((const vf2*)(xin + (size_t)row1 * 38 + 36));

    // ---- all row loads for both rows, non-temporal ----
    if (v0) {
        const size_t rb = (size_t)row0 * 15;
        load_row_nt(y_true + rb, T0);
        load_row_nt(y_pred + rb, P0);
        float M0[15];
        load_row_nt(mask + rb, M0);
#pragma unroll
        for (int c = 0; c < 15; c++) mb0 |= (M0[c] > 0.f ? 1u : 0u) << c;
    }
    if (v1) {
        const size_t rb = (size_t)row1 * 15;
        load_row_nt(y_true + rb, T1);
        load_row_nt(y_pred + rb, P1);
        float M1[15];
        load_row_nt(mask + rb, M1);
#pragma unroll
        for (int c = 0; c < 15; c++) mb1 |= (M1[c] > 0.f ? 1u : 0u) << c;
    }

    // ---- gate decode + table fetch (tiny, cached) ----
    int4 pk0 = make_int4(0, 0, 0, 0), pk1 = make_int4(0, 0, 0, 0);
    if (v0) {
        float beadf = isfinite(gb0.x) ? gb0.x : 0.f;
        float gatef = isfinite(gb0.y) ? gb0.y : 0.f;
        gatef = fminf(fmaxf(gatef, -1e6f), 1e6f);
        beadf = fminf(fmaxf(beadf, -1e6f), 1e6f);
        int rid = min(max((int)rintf(gatef) - 1, 0), NEXP - 1);
        int bid = min(max((int)rintf(beadf), 0), NBEAD - 1);
        pk0 = ptbl[rid * NBEAD + bid];
    }
    if (v1) {
        float beadf = isfinite(gb1.x) ? gb1.x : 0.f;
        float gatef = isfinite(gb1.y) ? gb1.y : 0.f;
        gatef = fminf(fmaxf(gatef, -1e6f), 1e6f);
        beadf = fminf(fmaxf(beadf, -1e6f), 1e6f);
        int rid = min(max((int)rintf(gatef) - 1, 0), NEXP - 1);
        int bid = min(max((int)rintf(beadf), 0), NBEAD - 1);
        pk1 = ptbl[rid * NBEAD + bid];
    }

    // ---- compute ----
    float result = 0.f;
    if (v0) result += row_loss(T0, P0, mb0, pk0, st);
    if (v1) result += row_loss(T1, P1, mb1, pk1, st);

    // ---- block reduction ----
#pragma unroll
    for (int off = 32; off > 0; off >>= 1)
        result += __shfl_down(result, off, 64);
    __syncthreads();  // protect scr reuse as red[]
    float* red = scr;
    int lane = tid & 63, wv = tid >> 6;
    if (lane == 0) red[wv] = result;
    __syncthreads();
    if (tid == 0) partial[blockIdx.x] = red[0] + red[1] + red[2] + red[3];
}

__global__ __launch_bounds__(256) void reduce_kernel(const float* __restrict__ partial,
                                                     float* __restrict__ out, int nblocks,
                                                     float inv_n) {
    __shared__ float red[4];
    float s = 0.f;
    for (int i = threadIdx.x; i < nblocks; i += 256) s += partial[i];
#pragma unroll
    for (int off = 32; off > 0; off >>= 1) s += __shfl_down(s, off, 64);
    int lane = threadIdx.x & 63, wv = threadIdx.x >> 6;
    if (lane == 0) red[wv] = s;
    __syncthreads();
    if (threadIdx.x == 0) out[0] = (red[0] + red[1] + red[2] + red[3]) * inv_n;
}

extern "C" void kernel_launch(void* const* d_in, const int* in_sizes, int n_in,
                              void* d_out, int out_size, void* d_ws, size_t ws_size,
                              hipStream_t stream) {
    const float* x = (const float*)d_in[0];
    const float* y_true = (const float*)d_in[1];
    const float* y_pred = (const float*)d_in[2];
    const float* mask = (const float*)d_in[3];
    const int* trip = (const int*)d_in[4];
    const int* valid = (const int*)d_in[5];
    float* out = (float*)d_out;

    int4* ptbl = (int4*)d_ws;                       // 72 * 16 B
    float* partial = (float*)((char*)d_ws + 4096);  // block partials

    const int n = in_sizes[1] / 15;  // N rows (y_true is N x 15)
    const int blocks = (n + 511) / 512;

    pack_tables<<<1, 128, 0, stream>>>(trip, valid, ptbl);
    loss_kernel<<<blocks, 256, 0, stream>>>(x, y_true, y_pred, mask, ptbl, partial, n);
    reduce_kernel<<<1, 256, 0, stream>>>(partial, out, blocks, 1.0f / (float)n);
}